// Round 4
// 362.949 us; speedup vs baseline: 1.1106x; 1.1106x over previous
//
#include <hip/hip_runtime.h>

typedef unsigned short ushort_t;
typedef __attribute__((ext_vector_type(8))) short bf16x8;
typedef __attribute__((ext_vector_type(4))) float f32x4;
typedef __attribute__((ext_vector_type(16))) float f32x16;
typedef __attribute__((ext_vector_type(2))) __bf16 bf16v2;

#define BN 4
#define SEQ 2048
#define DIM 1024
#define NH 16
#define HDIM 64
#define MROWS (BN*SEQ)   // 8192
#define QSCALE 0.18033688011112042f   // 0.125 * log2(e): folded into Q so p = exp2(s)

__device__ __forceinline__ float bf2f(ushort_t s){ return __uint_as_float(((unsigned)s) << 16); }
__device__ __forceinline__ ushort_t f2bf(float f){
  unsigned u = __float_as_uint(f);
  u += 0x7fffu + ((u >> 16) & 1u);   // round-to-nearest-even
  return (ushort_t)(u >> 16);
}
__device__ __forceinline__ unsigned pack2(float a, float b){
  return (unsigned)f2bf(a) | ((unsigned)f2bf(b) << 16);
}

// ---------------- LN stats: one block per row -> (mu, rstd) -----------------
__global__ __launch_bounds__(256) void stats_kernel(const float* __restrict__ x,
                                                    float* __restrict__ stats)
{
  int row = blockIdx.x;
  int t = threadIdx.x;
  float4 v = ((const float4*)(x + (size_t)row * DIM))[t];
  float s = v.x+v.y+v.z+v.w;
  float ss = v.x*v.x+v.y*v.y+v.z*v.z+v.w*v.w;
  #pragma unroll
  for (int o = 32; o > 0; o >>= 1){ s += __shfl_down(s, o); ss += __shfl_down(ss, o); }
  __shared__ float red[8];
  int wid = t >> 6;
  if ((t & 63) == 0){ red[wid] = s; red[4+wid] = ss; }
  __syncthreads();
  if (t == 0){
    float S0 = red[0]+red[1]+red[2]+red[3];
    float SS = red[4]+red[5]+red[6]+red[7];
    float mu = S0 * (1.f/DIM);
    float var = SS * (1.f/DIM) - mu*mu;
    ((float2*)stats)[row] = make_float2(mu, rsqrtf(var + 1e-5f));
  }
}

// ------- transpose + fp32->bf16 convert: dst[n][k] = src[k][n] * rowscale ---
__global__ __launch_bounds__(256) void cvt_t(const float* __restrict__ src,
                                             ushort_t* __restrict__ dst,
                                             int K, int N, float qscale)
{
  __shared__ float tile[64][65];
  int k0 = blockIdx.y*64, n0 = blockIdx.x*64;
  float sc = (n0 < 1024) ? qscale : 1.f;
  int t = threadIdx.x;
  int c = (t & 15) * 4, r = t >> 4;
  #pragma unroll
  for (int p = 0; p < 4; p++){
    float4 v = *(const float4*)(src + (size_t)(k0 + r + p*16)*N + n0 + c);
    tile[r+p*16][c]   = v.x; tile[r+p*16][c+1] = v.y;
    tile[r+p*16][c+2] = v.z; tile[r+p*16][c+3] = v.w;
  }
  __syncthreads();
  #pragma unroll
  for (int p = 0; p < 4; p++){
    int nn = r + p*16;
    ushort4 o;
    o.x = f2bf(tile[c+0][nn]*sc); o.y = f2bf(tile[c+1][nn]*sc);
    o.z = f2bf(tile[c+2][nn]*sc); o.w = f2bf(tile[c+3][nn]*sc);
    *(ushort4*)(dst + (size_t)(n0+nn)*K + k0 + c) = o;
  }
}

// ---------------- V transpose -> panel-contiguous V^T -----------------------
__global__ __launch_bounds__(256) void vtrans(const ushort_t* __restrict__ V,
                                              ushort_t* __restrict__ vt)
{
  __shared__ ushort_t tile[64][72];
  int bh = blockIdx.x >> 5, sc = blockIdx.x & 31;
  int t = threadIdx.x;
  const ushort_t* src = V + ((size_t)bh*SEQ + sc*64)*HDIM;
  #pragma unroll
  for (int p = 0; p < 2; p++){
    int idx = p*256 + t;
    int r = idx >> 3, c8 = (idx & 7)*8;
    *(uint4*)&tile[r][c8] = *(const uint4*)(src + (size_t)r*HDIM + c8);
  }
  __syncthreads();
  ushort_t* dstp = vt + ((size_t)(bh*32 + sc))*HDIM*64;
  #pragma unroll
  for (int p = 0; p < 2; p++){
    int idx = p*256 + t;
    int d = idx >> 3, c8 = (idx & 7)*8;
    uint4 u;
    u.x = (unsigned)tile[c8+0][d] | ((unsigned)tile[c8+1][d] << 16);
    u.y = (unsigned)tile[c8+2][d] | ((unsigned)tile[c8+3][d] << 16);
    u.z = (unsigned)tile[c8+4][d] | ((unsigned)tile[c8+5][d] << 16);
    u.w = (unsigned)tile[c8+6][d] | ((unsigned)tile[c8+7][d] << 16);
    *(uint4*)(dstp + (size_t)d*64 + c8) = u;
  }
}

// ---------------- MFMA GEMM (verified round 4; MODE1 bias scaled for Q) -----
template<int MODE, int NCOLS>
__global__ __launch_bounds__(256) void mfma_gemm(
    const void* __restrict__ Av,
    const ushort_t* __restrict__ BT,
    const float* __restrict__ bias,
    const float* __restrict__ stats,
    const float* __restrict__ gamma,
    const float* __restrict__ beta,
    void* __restrict__ Cv)
{
  __shared__ __align__(16) unsigned char smem[MODE ? 24576 : 17408];
  ushort_t (*As)[128][8] = (ushort_t(*)[128][8])smem;
  ushort_t (*Bs)[128][8] = (ushort_t(*)[128][8])(smem + 8192);
  float* gs  = (float*)(smem + 16384);
  float* bs2 = gs + 1024;

  int t = threadIdx.x;
  int lane = t & 63, w = t >> 6;
  int col = lane & 15, quad = lane >> 4;
  int n0 = blockIdx.x * 128, m0 = blockIdx.y * 128;
  int sr = t >> 1, h = t & 1;

  float mu = 0.f, rstd = 0.f;
  if (MODE == 1){
    *(float4*)&gs[t*4]  = ((const float4*)gamma)[t];
    *(float4*)&bs2[t*4] = ((const float4*)beta)[t];
    float2 st = ((const float2*)stats)[m0 + sr];
    mu = st.x; rstd = st.y;
  }

  f32x4 acc[4][4];
  #pragma unroll
  for (int i = 0; i < 4; i++)
    #pragma unroll
    for (int j = 0; j < 4; j++) acc[i][j] = (f32x4){0.f,0.f,0.f,0.f};

  int mbase = (w & 1)*64 + col;
  int nbase = (w >> 1)*64 + col;

  for (int k0 = 0; k0 < DIM; k0 += 32){
    uint4 aa0, aa1, bb0, bb1;
    float4 ax[4];
    if (MODE == 1){
      const float* xp = (const float*)Av + (size_t)(m0 + sr)*DIM + k0 + h*16;
      #pragma unroll
      for (int i = 0; i < 4; i++) ax[i] = *(const float4*)(xp + i*4);
    } else {
      const ushort_t* ap = (const ushort_t*)Av + (size_t)(m0 + sr)*DIM + k0 + h*16;
      aa0 = *(const uint4*)ap; aa1 = *(const uint4*)(ap + 8);
    }
    const ushort_t* bp = BT + (size_t)(n0 + sr)*DIM + k0 + h*16;
    bb0 = *(const uint4*)bp; bb1 = *(const uint4*)(bp + 8);

    __syncthreads();

    *(uint4*)&Bs[2*h  ][sr][0] = bb0;
    *(uint4*)&Bs[2*h+1][sr][0] = bb1;
    if (MODE == 1){
      float f[16];
      #pragma unroll
      for (int i = 0; i < 4; i++){
        float4 g = *(const float4*)&gs[k0 + h*16 + i*4];
        float4 b = *(const float4*)&bs2[k0 + h*16 + i*4];
        f[i*4+0] = (ax[i].x - mu)*rstd*g.x + b.x;
        f[i*4+1] = (ax[i].y - mu)*rstd*g.y + b.y;
        f[i*4+2] = (ax[i].z - mu)*rstd*g.z + b.z;
        f[i*4+3] = (ax[i].w - mu)*rstd*g.w + b.w;
      }
      uint4 p0, p1;
      p0.x = pack2(f[0],f[1]);  p0.y = pack2(f[2],f[3]);
      p0.z = pack2(f[4],f[5]);  p0.w = pack2(f[6],f[7]);
      p1.x = pack2(f[8],f[9]);  p1.y = pack2(f[10],f[11]);
      p1.z = pack2(f[12],f[13]); p1.w = pack2(f[14],f[15]);
      *(uint4*)&As[2*h  ][sr][0] = p0;
      *(uint4*)&As[2*h+1][sr][0] = p1;
    } else {
      *(uint4*)&As[2*h  ][sr][0] = aa0;
      *(uint4*)&As[2*h+1][sr][0] = aa1;
    }
    __syncthreads();

    bf16x8 af[4], bfr[4];
    #pragma unroll
    for (int i = 0; i < 4; i++){
      af[i]  = *(const bf16x8*)&As[quad][mbase + i*16][0];
      bfr[i] = *(const bf16x8*)&Bs[quad][nbase + i*16][0];
    }
    #pragma unroll
    for (int mt = 0; mt < 4; mt++)
      #pragma unroll
      for (int nt = 0; nt < 4; nt++)
        acc[mt][nt] = __builtin_amdgcn_mfma_f32_16x16x32_bf16(af[mt], bfr[nt], acc[mt][nt], 0, 0, 0);
  }

  float bscale = (MODE == 1 && n0 < 1024) ? QSCALE : 1.f;
  float bv[4];
  #pragma unroll
  for (int nt = 0; nt < 4; nt++) bv[nt] = bias[n0 + (w>>1)*64 + nt*16 + col] * bscale;

  if (MODE == 1){
    ushort_t (*Cs)[136] = (ushort_t(*)[136])smem;
    ushort_t* C = (ushort_t*)Cv;
    #pragma unroll
    for (int ph = 0; ph < 2; ph++){
      __syncthreads();
      if ((w & 1) == ph){
        #pragma unroll
        for (int mt = 0; mt < 4; mt++)
          #pragma unroll
          for (int nt = 0; nt < 4; nt++)
            #pragma unroll
            for (int r = 0; r < 4; r++)
              Cs[mt*16 + quad*4 + r][(w>>1)*64 + nt*16 + col] = f2bf(acc[mt][nt][r] + bv[nt]);
      }
      __syncthreads();
      #pragma unroll
      for (int p = 0; p < 4; p++){
        int id = p*256 + t;
        int row = id >> 4, cc = id & 15;
        uint4 u = *(const uint4*)&Cs[row][cc*8];
        int m = m0 + ph*64 + row;
        int n = n0 + cc*8;
        int which = n >> 10, hh = (n >> 6) & 15, d = n & 63;
        int b_ = m >> 11, s_ = m & (SEQ-1);
        *(uint4*)&C[((((size_t)which*BN + b_)*NH + hh)*SEQ + s_)*HDIM + d] = u;
      }
    }
  } else {
    float (*Cf)[132] = (float(*)[132])smem;
    float* C = (float*)Cv;
    #pragma unroll
    for (int ph = 0; ph < 4; ph++){
      __syncthreads();
      if ((w & 1) == (ph >> 1)){
        #pragma unroll
        for (int mi = 0; mi < 2; mi++){
          int mt = (ph & 1)*2 + mi;
          #pragma unroll
          for (int nt = 0; nt < 4; nt++)
            #pragma unroll
            for (int r = 0; r < 4; r++)
              Cf[mi*16 + quad*4 + r][(w>>1)*64 + nt*16 + col] = acc[mt][nt][r] + bv[nt];
        }
      }
      __syncthreads();
      #pragma unroll
      for (int p = 0; p < 4; p++){
        int id = p*256 + t;
        int row = id >> 5, cc = id & 31;
        float4 v = *(const float4*)&Cf[row][cc*4];
        int m = m0 + ph*32 + row;
        *(float4*)(C + (size_t)m*NCOLS + n0 + cc*4) = v;
      }
    }
  }
}

// ---------------- MFMA flash attention v7b: permuted-V + disjoint-Os --------
// v7 (round 3): validation PASSED (absmax 0.00195), dur 364us, but POST-TIMING
// tripwire diverged (absmax 0.12) -> suspected rare LDS hazard in the epilogue
// which reused the K/V staging region as Os across a barrier. v7b: Os gets a
// DISJOINT LDS region (+18K, still not the occupancy binder) so the epilogue
// is pure wave-private LDS -> both epilogue barriers removed, zero cross-wave
// LDS interaction after the main loop. Everything else identical to v7:
//
// KEY TRICK (v7): MFMA's sum_k A[m][k]B[k][n] is invariant under any k-perm
// applied to BOTH operands. The raw P words place key 8*(e>>2)+4*half+(e&3)
// at nominal slot k=8*half+e. Instead of exchanging P across lane-halves,
// load V's A-frag with the SAME permutation: element j reads key
// 8*(j>>2)+4*half+(j&3) = two aligned 8B reads Vs[2kc][d][4h..] /
// Vs[2kc+1][d][4h..]. Zero cross-lane ops for P.
// Pack: plain __bf16 casts (RNE; compiler fuses to v_cvt_pk_bf16_f32).
// Row-sum l on the matrix pipe: accL = mfma(ones, P_raw, accL); rows all
// identical -> l = accL[0]; denominator sums the SAME bf16-rounded P as PV.
__global__ __launch_bounds__(256) void attn_kernel(const ushort_t* __restrict__ qkv,
                                                   const ushort_t* __restrict__ vtp,
                                                   ushort_t* __restrict__ ctx)
{
  __shared__ __align__(16) unsigned char lds[36864];   // staging 16K | Os 4x4608 disjoint
  ushort_t (*Ks)[64][8] = (ushort_t(*)[64][8])lds;            // [8][64][8] dim-octet major
  ushort_t (*Vs)[64][8] = (ushort_t(*)[64][8])(lds + 8192);   // [8][64][8] key-octet major

  int t = threadIdx.x;
  int lane = t & 63, w = t >> 6;
  int m32 = lane & 31, half = lane >> 5;
  int id = blockIdx.x;
  int bh = (id & 7) | ((id >> 7) << 3);   // XCD-swizzle (L2 locality, r7-verified)
  int qb = (id >> 3) & 15;

  const size_t PL = (size_t)BN * NH * SEQ * HDIM;
  const ushort_t* Qg = qkv + (size_t)bh * (SEQ * HDIM);
  const ushort_t* Kg = Qg + PL;
  const ushort_t* Vt = vtp + (size_t)bh * 32 * (HDIM * 64);
  int qbase = qb*128 + w*32;

  // Q B-frags, fixed: B[k=dim][n=q]: lane q=m32, dims c*16 + half*8 + [0,8)
  bf16x8 qf[4];
  #pragma unroll
  for (int c = 0; c < 4; c++)
    qf[c] = *(const bf16x8*)(Qg + (size_t)(qbase + m32)*HDIM + c*16 + half*8);

  // all-ones A-frag for the l row-sum MFMA
  bf16x8 ones;
  #pragma unroll
  for (int i = 0; i < 8; i++) ones[i] = (short)0x3F80;

  f32x16 accO[2], accL;
  #pragma unroll
  for (int i = 0; i < 2; i++)
    #pragma unroll
    for (int r = 0; r < 16; r++) accO[i][r] = 0.f;
  #pragma unroll
  for (int r = 0; r < 16; r++) accL[r] = 0.f;

  int srow = t >> 2, sch = t & 3;
  const ushort_t* kp0 = Kg + (size_t)srow*HDIM + sch*16;
  const ushort_t* vp0 = Vt + (size_t)srow*64 + sch*16;

  uint4 kr0, kr1, vr0, vr1;
  kr0 = *(const uint4*)kp0;  kr1 = *(const uint4*)(kp0 + 8);
  vr0 = *(const uint4*)vp0;  vr1 = *(const uint4*)(vp0 + 8);

  for (int kt = 0; kt < 32; kt++){
    __syncthreads();
    *(uint4*)&Ks[sch*2  ][srow][0] = kr0;
    *(uint4*)&Ks[sch*2+1][srow][0] = kr1;
    *(uint4*)&Vs[sch*2  ][srow][0] = vr0;
    *(uint4*)&Vs[sch*2+1][srow][0] = vr1;
    __syncthreads();

    if (kt < 31){
      const ushort_t* kp = kp0 + (size_t)(kt+1)*64*HDIM;
      const ushort_t* vp = vp0 + (size_t)(kt+1)*HDIM*64;
      kr0 = *(const uint4*)kp;  kr1 = *(const uint4*)(kp + 8);
      vr0 = *(const uint4*)vp;  vr1 = *(const uint4*)(vp + 8);
    }

    // ---- per key-tile of 32: S^T = K Q^T, p = exp2(s), pack (RAW order) ----
    bf16x8 pb[4];
    #pragma unroll
    for (int mt = 0; mt < 2; mt++){
      f32x16 z;
      #pragma unroll
      for (int r = 0; r < 16; r++) z[r] = 0.f;
      #pragma unroll
      for (int c = 0; c < 4; c++){
        bf16x8 af = *(const bf16x8*)&Ks[2*c + half][mt*32 + m32][0];
        z = __builtin_amdgcn_mfma_f32_32x32x16_bf16(af, qf[c], z, 0, 0, 0);
      }
      unsigned u[8];
      #pragma unroll
      for (int i = 0; i < 8; i++){
        float p0 = __builtin_amdgcn_exp2f(z[2*i]);
        float p1 = __builtin_amdgcn_exp2f(z[2*i+1]);
        bf16v2 hh; hh.x = (__bf16)p0; hh.y = (__bf16)p1;
        u[i] = __builtin_bit_cast(unsigned, hh);
      }
      #pragma unroll
      for (int cc = 0; cc < 2; cc++){
        union { uint4 q; bf16x8 b; } cvt;
        cvt.q = make_uint4(u[4*cc+0], u[4*cc+1], u[4*cc+2], u[4*cc+3]);
        pb[mt*2 + cc] = cvt.b;   // raw order: slot (h,e) holds key 8(e>>2)+4h+(e&3)
      }
    }

    // ---- l row-sum on the matrix pipe: accL += ones * P (perm-invariant) ----
    #pragma unroll
    for (int kc = 0; kc < 4; kc++)
      accL = __builtin_amdgcn_mfma_f32_32x32x16_bf16(ones, pb[kc], accL, 0, 0, 0);

    // ---- O^T += V^T P^T with k-permuted V A-frags (two 8B reads each) ----
    #pragma unroll
    for (int kc = 0; kc < 4; kc++){
      #pragma unroll
      for (int md = 0; md < 2; md++){
        int dd = md*32 + m32;
        union { bf16x8 v8; uint2 u2[2]; } vv;
        vv.u2[0] = *(const uint2*)&Vs[2*kc  ][dd][4*half];   // keys 4h+0..3 of chunk
        vv.u2[1] = *(const uint2*)&Vs[2*kc+1][dd][4*half];   // keys 8+4h+0..3
        accO[md] = __builtin_amdgcn_mfma_f32_32x32x16_bf16(vv.v8, pb[kc], accO[md], 0, 0, 0);
      }
    }
  }

  // ---- epilogue: l per q = accL[0] (all rows identical, both halves same) --
  // Os region is DISJOINT from staging and wave-private: no barriers needed.
  float inv = 1.f / accL[0];

  ushort_t (*Os)[72] = (ushort_t(*)[72])(lds + 18432 + w*4608);   // [32 q][64+8 d]
  #pragma unroll
  for (int md = 0; md < 2; md++)
    #pragma unroll
    for (int g = 0; g < 4; g++){
      // regs 4g..4g+3 = d: 8g + 4*half + 32*md + [0,4)
      int d0 = 8*g + 4*half + 32*md;
      unsigned lo = pack2(accO[md][4*g+0]*inv, accO[md][4*g+1]*inv);
      unsigned hi = pack2(accO[md][4*g+2]*inv, accO[md][4*g+3]*inv);
      *(uint2*)&Os[m32][d0] = make_uint2(lo, hi);
    }

  int b_ = bh >> 4, h_ = bh & 15;
  #pragma unroll
  for (int k = 0; k < 4; k++){
    int row = k*8 + (lane >> 3);
    uint4 u = *(const uint4*)&Os[row][(lane & 7)*8];
    *(uint4*)(ctx + ((size_t)(b_*SEQ + qb*128 + w*32 + row))*DIM + h_*HDIM + (lane & 7)*8) = u;
  }
}

extern "C" void kernel_launch(void* const* d_in, const int* in_sizes, int n_in,
                              void* d_out, int out_size, void* d_ws, size_t ws_size,
                              hipStream_t stream)
{
  const float* x      = (const float*)d_in[0];
  const float* gamma  = (const float*)d_in[1];
  const float* beta   = (const float*)d_in[2];
  const float* w_qkv  = (const float*)d_in[3];
  const float* b_qkv  = (const float*)d_in[4];
  const float* w_proj = (const float*)d_in[5];
  const float* b_proj = (const float*)d_in[6];

  // ws (64 MB), timeline-overlapped (see round-5 comment)
  char* ws = (char*)d_ws;
  ushort_t* wqkvT  = (ushort_t*)ws;
  float*    stats  = (float*)(ws + 6u*1024*1024);
  ushort_t* vt     = (ushort_t*)ws;
  ushort_t* wprojT = (ushort_t*)ws;
  ushort_t* qkv    = (ushort_t*)(ws + 16u*1024*1024);
  ushort_t* Vplane = (ushort_t*)(ws + 48u*1024*1024);
  ushort_t* ctx    = (ushort_t*)(ws + 48u*1024*1024);

  stats_kernel<<<MROWS, 256, 0, stream>>>(x, stats);
  cvt_t<<<dim3(3*DIM/64, DIM/64), 256, 0, stream>>>(w_qkv, wqkvT, DIM, 3*DIM, QSCALE);
  mfma_gemm<1, 3*DIM><<<dim3(3*DIM/128, MROWS/128), 256, 0, stream>>>(
      x, wqkvT, b_qkv, stats, gamma, beta, qkv);
  vtrans<<<BN*NH*(SEQ/64), 256, 0, stream>>>(Vplane, vt);
  attn_kernel<<<BN*NH*(SEQ/128), 256, 0, stream>>>(qkv, vt, ctx);
  cvt_t<<<dim3(DIM/64, DIM/64), 256, 0, stream>>>(w_proj, wprojT, DIM, DIM, 1.f);
  mfma_gemm<0, DIM><<<dim3(DIM/128, MROWS/128), 256, 0, stream>>>(
      ctx, wprojT, b_proj, nullptr, nullptr, nullptr, d_out);
}

// Round 5
// 320.019 us; speedup vs baseline: 1.2595x; 1.1341x over previous
//
#include <hip/hip_runtime.h>

typedef unsigned short ushort_t;
typedef __attribute__((ext_vector_type(8))) short bf16x8;
typedef __attribute__((ext_vector_type(4))) float f32x4;
typedef __attribute__((ext_vector_type(16))) float f32x16;
typedef __attribute__((ext_vector_type(2))) __bf16 bf16v2;

#define BN 4
#define SEQ 2048
#define DIM 1024
#define NH 16
#define HDIM 64
#define MROWS (BN*SEQ)   // 8192
#define QSCALE 0.18033688011112042f   // 0.125 * log2(e): folded into Q so p = exp2(s)

__device__ __forceinline__ float bf2f(ushort_t s){ return __uint_as_float(((unsigned)s) << 16); }
__device__ __forceinline__ ushort_t f2bf(float f){
  unsigned u = __float_as_uint(f);
  u += 0x7fffu + ((u >> 16) & 1u);   // round-to-nearest-even
  return (ushort_t)(u >> 16);
}
__device__ __forceinline__ unsigned pack2(float a, float b){
  return (unsigned)f2bf(a) | ((unsigned)f2bf(b) << 16);
}

// ------- fused LN: stats + normalize + bf16 pack, ONE pass over x -----------
// (round 5: replaces stats_kernel + the 24x-redundant LN/pack inside the QKV
// GEMM's A-staging. x row is already in registers after the reduction;
// mu/rstd broadcast via LDS; output xnb is bit-identical to what MODE-1
// staging produced: same reduction order, same RNE pack.)
__global__ __launch_bounds__(256) void ln_kernel(const float* __restrict__ x,
                                                 const float* __restrict__ gamma,
                                                 const float* __restrict__ beta,
                                                 ushort_t* __restrict__ xnb)
{
  int row = blockIdx.x;
  int t = threadIdx.x;
  float4 v = ((const float4*)(x + (size_t)row * DIM))[t];
  float s = v.x+v.y+v.z+v.w;
  float ss = v.x*v.x+v.y*v.y+v.z*v.z+v.w*v.w;
  #pragma unroll
  for (int o = 32; o > 0; o >>= 1){ s += __shfl_down(s, o); ss += __shfl_down(ss, o); }
  __shared__ float red[10];
  int wid = t >> 6;
  if ((t & 63) == 0){ red[wid] = s; red[4+wid] = ss; }
  __syncthreads();
  if (t == 0){
    float S0 = red[0]+red[1]+red[2]+red[3];
    float SS = red[4]+red[5]+red[6]+red[7];
    float mu = S0 * (1.f/DIM);
    float var = SS * (1.f/DIM) - mu*mu;
    red[8] = mu; red[9] = rsqrtf(var + 1e-5f);
  }
  __syncthreads();
  float mu = red[8], rstd = red[9];
  float4 g = ((const float4*)gamma)[t];
  float4 b = ((const float4*)beta)[t];
  float f0 = (v.x - mu)*rstd*g.x + b.x;
  float f1 = (v.y - mu)*rstd*g.y + b.y;
  float f2 = (v.z - mu)*rstd*g.z + b.z;
  float f3 = (v.w - mu)*rstd*g.w + b.w;
  *(uint2*)(xnb + (size_t)row*DIM + t*4) = make_uint2(pack2(f0,f1), pack2(f2,f3));
}

// ------- transpose + fp32->bf16 convert: dst[n][k] = src[k][n] * rowscale ---
__global__ __launch_bounds__(256) void cvt_t(const float* __restrict__ src,
                                             ushort_t* __restrict__ dst,
                                             int K, int N, float qscale)
{
  __shared__ float tile[64][65];
  int k0 = blockIdx.y*64, n0 = blockIdx.x*64;
  float sc = (n0 < 1024) ? qscale : 1.f;
  int t = threadIdx.x;
  int c = (t & 15) * 4, r = t >> 4;
  #pragma unroll
  for (int p = 0; p < 4; p++){
    float4 v = *(const float4*)(src + (size_t)(k0 + r + p*16)*N + n0 + c);
    tile[r+p*16][c]   = v.x; tile[r+p*16][c+1] = v.y;
    tile[r+p*16][c+2] = v.z; tile[r+p*16][c+3] = v.w;
  }
  __syncthreads();
  #pragma unroll
  for (int p = 0; p < 4; p++){
    int nn = r + p*16;
    ushort4 o;
    o.x = f2bf(tile[c+0][nn]*sc); o.y = f2bf(tile[c+1][nn]*sc);
    o.z = f2bf(tile[c+2][nn]*sc); o.w = f2bf(tile[c+3][nn]*sc);
    *(ushort4*)(dst + (size_t)(n0+nn)*K + k0 + c) = o;
  }
}

// ---------------- V transpose -> panel-contiguous V^T -----------------------
__global__ __launch_bounds__(256) void vtrans(const ushort_t* __restrict__ V,
                                              ushort_t* __restrict__ vt)
{
  __shared__ ushort_t tile[64][72];
  int bh = blockIdx.x >> 5, sc = blockIdx.x & 31;
  int t = threadIdx.x;
  const ushort_t* src = V + ((size_t)bh*SEQ + sc*64)*HDIM;
  #pragma unroll
  for (int p = 0; p < 2; p++){
    int idx = p*256 + t;
    int r = idx >> 3, c8 = (idx & 7)*8;
    *(uint4*)&tile[r][c8] = *(const uint4*)(src + (size_t)r*HDIM + c8);
  }
  __syncthreads();
  ushort_t* dstp = vt + ((size_t)(bh*32 + sc))*HDIM*64;
  #pragma unroll
  for (int p = 0; p < 2; p++){
    int idx = p*256 + t;
    int d = idx >> 3, c8 = (idx & 7)*8;
    uint4 u;
    u.x = (unsigned)tile[c8+0][d] | ((unsigned)tile[c8+1][d] << 16);
    u.y = (unsigned)tile[c8+2][d] | ((unsigned)tile[c8+3][d] << 16);
    u.z = (unsigned)tile[c8+4][d] | ((unsigned)tile[c8+5][d] << 16);
    u.w = (unsigned)tile[c8+6][d] | ((unsigned)tile[c8+7][d] << 16);
    *(uint4*)(dstp + (size_t)d*64 + c8) = u;
  }
}

// ---------------- MFMA GEMM: bf16 A/B staging for BOTH modes ----------------
// MODE 0: f32 row-major C (proj). MODE 2: bf16 qkv-layout C + Q-scaled bias
// (QKV). Round 5: the LN+pack fused A-path (old MODE 1) is gone — it re-did
// LN 24x (once per N-tile). A is now precomputed bf16 (ln_kernel), so staging
// is pure uint4 copies for both operands.
template<int MODE, int NCOLS>
__global__ __launch_bounds__(256) void mfma_gemm(
    const ushort_t* __restrict__ A,
    const ushort_t* __restrict__ BT,
    const float* __restrict__ bias,
    void* __restrict__ Cv)
{
  __shared__ __align__(16) unsigned char smem[17408];
  ushort_t (*As)[128][8] = (ushort_t(*)[128][8])smem;
  ushort_t (*Bs)[128][8] = (ushort_t(*)[128][8])(smem + 8192);

  int t = threadIdx.x;
  int lane = t & 63, w = t >> 6;
  int col = lane & 15, quad = lane >> 4;
  int n0 = blockIdx.x * 128, m0 = blockIdx.y * 128;
  int sr = t >> 1, h = t & 1;

  f32x4 acc[4][4];
  #pragma unroll
  for (int i = 0; i < 4; i++)
    #pragma unroll
    for (int j = 0; j < 4; j++) acc[i][j] = (f32x4){0.f,0.f,0.f,0.f};

  int mbase = (w & 1)*64 + col;
  int nbase = (w >> 1)*64 + col;

  for (int k0 = 0; k0 < DIM; k0 += 32){
    const ushort_t* ap = A + (size_t)(m0 + sr)*DIM + k0 + h*16;
    uint4 aa0 = *(const uint4*)ap, aa1 = *(const uint4*)(ap + 8);
    const ushort_t* bp = BT + (size_t)(n0 + sr)*DIM + k0 + h*16;
    uint4 bb0 = *(const uint4*)bp, bb1 = *(const uint4*)(bp + 8);

    __syncthreads();
    *(uint4*)&As[2*h  ][sr][0] = aa0;
    *(uint4*)&As[2*h+1][sr][0] = aa1;
    *(uint4*)&Bs[2*h  ][sr][0] = bb0;
    *(uint4*)&Bs[2*h+1][sr][0] = bb1;
    __syncthreads();

    bf16x8 af[4], bfr[4];
    #pragma unroll
    for (int i = 0; i < 4; i++){
      af[i]  = *(const bf16x8*)&As[quad][mbase + i*16][0];
      bfr[i] = *(const bf16x8*)&Bs[quad][nbase + i*16][0];
    }
    #pragma unroll
    for (int mt = 0; mt < 4; mt++)
      #pragma unroll
      for (int nt = 0; nt < 4; nt++)
        acc[mt][nt] = __builtin_amdgcn_mfma_f32_16x16x32_bf16(af[mt], bfr[nt], acc[mt][nt], 0, 0, 0);
  }

  float bscale = (MODE == 2 && n0 < 1024) ? QSCALE : 1.f;
  float bv[4];
  #pragma unroll
  for (int nt = 0; nt < 4; nt++) bv[nt] = bias[n0 + (w>>1)*64 + nt*16 + col] * bscale;

  if (MODE == 2){
    ushort_t (*Cs)[136] = (ushort_t(*)[136])smem;
    ushort_t* C = (ushort_t*)Cv;
    #pragma unroll
    for (int ph = 0; ph < 2; ph++){
      __syncthreads();
      if ((w & 1) == ph){
        #pragma unroll
        for (int mt = 0; mt < 4; mt++)
          #pragma unroll
          for (int nt = 0; nt < 4; nt++)
            #pragma unroll
            for (int r = 0; r < 4; r++)
              Cs[mt*16 + quad*4 + r][(w>>1)*64 + nt*16 + col] = f2bf(acc[mt][nt][r] + bv[nt]);
      }
      __syncthreads();
      #pragma unroll
      for (int p = 0; p < 4; p++){
        int id = p*256 + t;
        int row = id >> 4, cc = id & 15;
        uint4 u = *(const uint4*)&Cs[row][cc*8];
        int m = m0 + ph*64 + row;
        int n = n0 + cc*8;
        int which = n >> 10, hh = (n >> 6) & 15, d = n & 63;
        int b_ = m >> 11, s_ = m & (SEQ-1);
        *(uint4*)&C[((((size_t)which*BN + b_)*NH + hh)*SEQ + s_)*HDIM + d] = u;
      }
    }
  } else {
    float (*Cf)[132] = (float(*)[132])smem;
    float* C = (float*)Cv;
    #pragma unroll
    for (int ph = 0; ph < 4; ph++){
      __syncthreads();
      if ((w & 1) == (ph >> 1)){
        #pragma unroll
        for (int mi = 0; mi < 2; mi++){
          int mt = (ph & 1)*2 + mi;
          #pragma unroll
          for (int nt = 0; nt < 4; nt++)
            #pragma unroll
            for (int r = 0; r < 4; r++)
              Cf[mi*16 + quad*4 + r][(w>>1)*64 + nt*16 + col] = acc[mt][nt][r] + bv[nt];
        }
      }
      __syncthreads();
      #pragma unroll
      for (int p = 0; p < 4; p++){
        int id = p*256 + t;
        int row = id >> 5, cc = id & 31;
        float4 v = *(const float4*)&Cf[row][cc*4];
        int m = m0 + ph*32 + row;
        *(float4*)(C + (size_t)m*NCOLS + n0 + cc*4) = v;
      }
    }
  }
}

// ---------------- MFMA flash attention v7b: permuted-V + disjoint-Os --------
// (verified round 4: passed, attn off the top-5; unchanged this round)
// KEY TRICK (v7): MFMA's sum_k A[m][k]B[k][n] is invariant under any k-perm
// applied to BOTH operands. The raw P words place key 8*(e>>2)+4*half+(e&3)
// at nominal slot k=8*half+e. Instead of exchanging P across lane-halves,
// load V's A-frag with the SAME permutation: element j reads key
// 8*(j>>2)+4*half+(j&3) = two aligned 8B reads Vs[2kc][d][4h..] /
// Vs[2kc+1][d][4h..]. Zero cross-lane ops for P.
// Pack: plain __bf16 casts (RNE; compiler fuses to v_cvt_pk_bf16_f32).
// Row-sum l on the matrix pipe: accL = mfma(ones, P_raw, accL); rows all
// identical -> l = accL[0]; denominator sums the SAME bf16-rounded P as PV.
__global__ __launch_bounds__(256) void attn_kernel(const ushort_t* __restrict__ qkv,
                                                   const ushort_t* __restrict__ vtp,
                                                   ushort_t* __restrict__ ctx)
{
  __shared__ __align__(16) unsigned char lds[36864];   // staging 16K | Os 4x4608 disjoint
  ushort_t (*Ks)[64][8] = (ushort_t(*)[64][8])lds;            // [8][64][8] dim-octet major
  ushort_t (*Vs)[64][8] = (ushort_t(*)[64][8])(lds + 8192);   // [8][64][8] key-octet major

  int t = threadIdx.x;
  int lane = t & 63, w = t >> 6;
  int m32 = lane & 31, half = lane >> 5;
  int id = blockIdx.x;
  int bh = (id & 7) | ((id >> 7) << 3);   // XCD-swizzle (L2 locality, r7-verified)
  int qb = (id >> 3) & 15;

  const size_t PL = (size_t)BN * NH * SEQ * HDIM;
  const ushort_t* Qg = qkv + (size_t)bh * (SEQ * HDIM);
  const ushort_t* Kg = Qg + PL;
  const ushort_t* Vt = vtp + (size_t)bh * 32 * (HDIM * 64);
  int qbase = qb*128 + w*32;

  // Q B-frags, fixed: B[k=dim][n=q]: lane q=m32, dims c*16 + half*8 + [0,8)
  bf16x8 qf[4];
  #pragma unroll
  for (int c = 0; c < 4; c++)
    qf[c] = *(const bf16x8*)(Qg + (size_t)(qbase + m32)*HDIM + c*16 + half*8);

  // all-ones A-frag for the l row-sum MFMA
  bf16x8 ones;
  #pragma unroll
  for (int i = 0; i < 8; i++) ones[i] = (short)0x3F80;

  f32x16 accO[2], accL;
  #pragma unroll
  for (int i = 0; i < 2; i++)
    #pragma unroll
    for (int r = 0; r < 16; r++) accO[i][r] = 0.f;
  #pragma unroll
  for (int r = 0; r < 16; r++) accL[r] = 0.f;

  int srow = t >> 2, sch = t & 3;
  const ushort_t* kp0 = Kg + (size_t)srow*HDIM + sch*16;
  const ushort_t* vp0 = Vt + (size_t)srow*64 + sch*16;

  uint4 kr0, kr1, vr0, vr1;
  kr0 = *(const uint4*)kp0;  kr1 = *(const uint4*)(kp0 + 8);
  vr0 = *(const uint4*)vp0;  vr1 = *(const uint4*)(vp0 + 8);

  for (int kt = 0; kt < 32; kt++){
    __syncthreads();
    *(uint4*)&Ks[sch*2  ][srow][0] = kr0;
    *(uint4*)&Ks[sch*2+1][srow][0] = kr1;
    *(uint4*)&Vs[sch*2  ][srow][0] = vr0;
    *(uint4*)&Vs[sch*2+1][srow][0] = vr1;
    __syncthreads();

    if (kt < 31){
      const ushort_t* kp = kp0 + (size_t)(kt+1)*64*HDIM;
      const ushort_t* vp = vp0 + (size_t)(kt+1)*HDIM*64;
      kr0 = *(const uint4*)kp;  kr1 = *(const uint4*)(kp + 8);
      vr0 = *(const uint4*)vp;  vr1 = *(const uint4*)(vp + 8);
    }

    // ---- per key-tile of 32: S^T = K Q^T, p = exp2(s), pack (RAW order) ----
    bf16x8 pb[4];
    #pragma unroll
    for (int mt = 0; mt < 2; mt++){
      f32x16 z;
      #pragma unroll
      for (int r = 0; r < 16; r++) z[r] = 0.f;
      #pragma unroll
      for (int c = 0; c < 4; c++){
        bf16x8 af = *(const bf16x8*)&Ks[2*c + half][mt*32 + m32][0];
        z = __builtin_amdgcn_mfma_f32_32x32x16_bf16(af, qf[c], z, 0, 0, 0);
      }
      unsigned u[8];
      #pragma unroll
      for (int i = 0; i < 8; i++){
        float p0 = __builtin_amdgcn_exp2f(z[2*i]);
        float p1 = __builtin_amdgcn_exp2f(z[2*i+1]);
        bf16v2 hh; hh.x = (__bf16)p0; hh.y = (__bf16)p1;
        u[i] = __builtin_bit_cast(unsigned, hh);
      }
      #pragma unroll
      for (int cc = 0; cc < 2; cc++){
        union { uint4 q; bf16x8 b; } cvt;
        cvt.q = make_uint4(u[4*cc+0], u[4*cc+1], u[4*cc+2], u[4*cc+3]);
        pb[mt*2 + cc] = cvt.b;   // raw order: slot (h,e) holds key 8(e>>2)+4h+(e&3)
      }
    }

    // ---- l row-sum on the matrix pipe: accL += ones * P (perm-invariant) ----
    #pragma unroll
    for (int kc = 0; kc < 4; kc++)
      accL = __builtin_amdgcn_mfma_f32_32x32x16_bf16(ones, pb[kc], accL, 0, 0, 0);

    // ---- O^T += V^T P^T with k-permuted V A-frags (two 8B reads each) ----
    #pragma unroll
    for (int kc = 0; kc < 4; kc++){
      #pragma unroll
      for (int md = 0; md < 2; md++){
        int dd = md*32 + m32;
        union { bf16x8 v8; uint2 u2[2]; } vv;
        vv.u2[0] = *(const uint2*)&Vs[2*kc  ][dd][4*half];   // keys 4h+0..3 of chunk
        vv.u2[1] = *(const uint2*)&Vs[2*kc+1][dd][4*half];   // keys 8+4h+0..3
        accO[md] = __builtin_amdgcn_mfma_f32_32x32x16_bf16(vv.v8, pb[kc], accO[md], 0, 0, 0);
      }
    }
  }

  // ---- epilogue: l per q = accL[0] (all rows identical, both halves same) --
  // Os region is DISJOINT from staging and wave-private: no barriers needed.
  float inv = 1.f / accL[0];

  ushort_t (*Os)[72] = (ushort_t(*)[72])(lds + 18432 + w*4608);   // [32 q][64+8 d]
  #pragma unroll
  for (int md = 0; md < 2; md++)
    #pragma unroll
    for (int g = 0; g < 4; g++){
      // regs 4g..4g+3 = d: 8g + 4*half + 32*md + [0,4)
      int d0 = 8*g + 4*half + 32*md;
      unsigned lo = pack2(accO[md][4*g+0]*inv, accO[md][4*g+1]*inv);
      unsigned hi = pack2(accO[md][4*g+2]*inv, accO[md][4*g+3]*inv);
      *(uint2*)&Os[m32][d0] = make_uint2(lo, hi);
    }

  int b_ = bh >> 4, h_ = bh & 15;
  #pragma unroll
  for (int k = 0; k < 4; k++){
    int row = k*8 + (lane >> 3);
    uint4 u = *(const uint4*)&Os[row][(lane & 7)*8];
    *(uint4*)(ctx + ((size_t)(b_*SEQ + qb*128 + w*32 + row))*DIM + h_*HDIM + (lane & 7)*8) = u;
  }
}

extern "C" void kernel_launch(void* const* d_in, const int* in_sizes, int n_in,
                              void* d_out, int out_size, void* d_ws, size_t ws_size,
                              hipStream_t stream)
{
  const float* x      = (const float*)d_in[0];
  const float* gamma  = (const float*)d_in[1];
  const float* beta   = (const float*)d_in[2];
  const float* w_qkv  = (const float*)d_in[3];
  const float* b_qkv  = (const float*)d_in[4];
  const float* w_proj = (const float*)d_in[5];
  const float* b_proj = (const float*)d_in[6];

  // ws (64 MB), timeline-overlapped:
  //   wqkvT  0..6MB      (written cvt_t#1, read QKV GEMM)
  //   vt     0..16MB     (written vtrans after wqkvT dead, read attn)
  //   wprojT 0..2MB      (written cvt_t#2 after attn, read proj GEMM)
  //   qkv    16..64MB    (written QKV GEMM; Q,K read by attn; V by vtrans)
  //   ctx    48..64MB    (overwrites V plane after vtrans copied it)
  // xnb (16MB bf16 LN output) lives in the FIRST HALF OF d_out (32MB f32):
  // dead by the time the proj GEMM rewrites all of d_out; rewritten from x
  // every launch -> deterministic across graph replays.
  char* ws = (char*)d_ws;
  ushort_t* wqkvT  = (ushort_t*)ws;
  ushort_t* vt     = (ushort_t*)ws;
  ushort_t* wprojT = (ushort_t*)ws;
  ushort_t* qkv    = (ushort_t*)(ws + 16u*1024*1024);
  ushort_t* Vplane = (ushort_t*)(ws + 48u*1024*1024);
  ushort_t* ctx    = (ushort_t*)(ws + 48u*1024*1024);
  ushort_t* xnb    = (ushort_t*)d_out;

  ln_kernel<<<MROWS, 256, 0, stream>>>(x, gamma, beta, xnb);
  cvt_t<<<dim3(3*DIM/64, DIM/64), 256, 0, stream>>>(w_qkv, wqkvT, DIM, 3*DIM, QSCALE);
  mfma_gemm<2, 3*DIM><<<dim3(3*DIM/128, MROWS/128), 256, 0, stream>>>(
      xnb, wqkvT, b_qkv, qkv);
  vtrans<<<BN*NH*(SEQ/64), 256, 0, stream>>>(Vplane, vt);
  attn_kernel<<<BN*NH*(SEQ/128), 256, 0, stream>>>(qkv, vt, ctx);
  cvt_t<<<dim3(DIM/64, DIM/64), 256, 0, stream>>>(w_proj, wprojT, DIM, DIM, 1.f);
  mfma_gemm<0, DIM><<<dim3(DIM/128, MROWS/128), 256, 0, stream>>>(
      ctx, wprojT, b_proj, d_out);
}

// Round 8
// 313.707 us; speedup vs baseline: 1.2849x; 1.0201x over previous
//
#include <hip/hip_runtime.h>

typedef unsigned short ushort_t;
typedef __attribute__((ext_vector_type(8))) short bf16x8;
typedef __attribute__((ext_vector_type(4))) float f32x4;
typedef __attribute__((ext_vector_type(16))) float f32x16;
typedef __attribute__((ext_vector_type(2))) __bf16 bf16v2;

#define BN 4
#define SEQ 2048
#define DIM 1024
#define NH 16
#define HDIM 64
#define MROWS (BN*SEQ)   // 8192
#define QSCALE 0.18033688011112042f   // 0.125 * log2(e): folded into Q so p = exp2(s)

__device__ __forceinline__ float bf2f(ushort_t s){ return __uint_as_float(((unsigned)s) << 16); }
__device__ __forceinline__ ushort_t f2bf(float f){
  unsigned u = __float_as_uint(f);
  u += 0x7fffu + ((u >> 16) & 1u);   // round-to-nearest-even
  return (ushort_t)(u >> 16);
}
__device__ __forceinline__ unsigned pack2(float a, float b){
  return (unsigned)f2bf(a) | ((unsigned)f2bf(b) << 16);
}

// ------- fused LN: stats + normalize + bf16 pack, ONE pass over x -----------
__global__ __launch_bounds__(256) void ln_kernel(const float* __restrict__ x,
                                                 const float* __restrict__ gamma,
                                                 const float* __restrict__ beta,
                                                 ushort_t* __restrict__ xnb)
{
  int row = blockIdx.x;
  int t = threadIdx.x;
  float4 v = ((const float4*)(x + (size_t)row * DIM))[t];
  float s = v.x+v.y+v.z+v.w;
  float ss = v.x*v.x+v.y*v.y+v.z*v.z+v.w*v.w;
  #pragma unroll
  for (int o = 32; o > 0; o >>= 1){ s += __shfl_down(s, o); ss += __shfl_down(ss, o); }
  __shared__ float red[10];
  int wid = t >> 6;
  if ((t & 63) == 0){ red[wid] = s; red[4+wid] = ss; }
  __syncthreads();
  if (t == 0){
    float S0 = red[0]+red[1]+red[2]+red[3];
    float SS = red[4]+red[5]+red[6]+red[7];
    float mu = S0 * (1.f/DIM);
    float var = SS * (1.f/DIM) - mu*mu;
    red[8] = mu; red[9] = rsqrtf(var + 1e-5f);
  }
  __syncthreads();
  float mu = red[8], rstd = red[9];
  float4 g = ((const float4*)gamma)[t];
  float4 b = ((const float4*)beta)[t];
  float f0 = (v.x - mu)*rstd*g.x + b.x;
  float f1 = (v.y - mu)*rstd*g.y + b.y;
  float f2 = (v.z - mu)*rstd*g.z + b.z;
  float f3 = (v.w - mu)*rstd*g.w + b.w;
  *(uint2*)(xnb + (size_t)row*DIM + t*4) = make_uint2(pack2(f0,f1), pack2(f2,f3));
}

// ------- transpose + fp32->bf16 convert: dst[n][k] = src[k][n] * rowscale ---
__global__ __launch_bounds__(256) void cvt_t(const float* __restrict__ src,
                                             ushort_t* __restrict__ dst,
                                             int K, int N, float qscale)
{
  __shared__ float tile[64][65];
  int k0 = blockIdx.y*64, n0 = blockIdx.x*64;
  float sc = (n0 < 1024) ? qscale : 1.f;
  int t = threadIdx.x;
  int c = (t & 15) * 4, r = t >> 4;
  #pragma unroll
  for (int p = 0; p < 4; p++){
    float4 v = *(const float4*)(src + (size_t)(k0 + r + p*16)*N + n0 + c);
    tile[r+p*16][c]   = v.x; tile[r+p*16][c+1] = v.y;
    tile[r+p*16][c+2] = v.z; tile[r+p*16][c+3] = v.w;
  }
  __syncthreads();
  #pragma unroll
  for (int p = 0; p < 4; p++){
    int nn = r + p*16;
    ushort4 o;
    o.x = f2bf(tile[c+0][nn]*sc); o.y = f2bf(tile[c+1][nn]*sc);
    o.z = f2bf(tile[c+2][nn]*sc); o.w = f2bf(tile[c+3][nn]*sc);
    *(ushort4*)(dst + (size_t)(n0+nn)*K + k0 + c) = o;
  }
}

// ---------------- V transpose -> panel-contiguous V^T -----------------------
__global__ __launch_bounds__(256) void vtrans(const ushort_t* __restrict__ V,
                                              ushort_t* __restrict__ vt)
{
  __shared__ ushort_t tile[64][72];
  int bh = blockIdx.x >> 5, sc = blockIdx.x & 31;
  int t = threadIdx.x;
  const ushort_t* src = V + ((size_t)bh*SEQ + sc*64)*HDIM;
  #pragma unroll
  for (int p = 0; p < 2; p++){
    int idx = p*256 + t;
    int r = idx >> 3, c8 = (idx & 7)*8;
    *(uint4*)&tile[r][c8] = *(const uint4*)(src + (size_t)r*HDIM + c8);
  }
  __syncthreads();
  ushort_t* dstp = vt + ((size_t)(bh*32 + sc))*HDIM*64;
  #pragma unroll
  for (int p = 0; p < 2; p++){
    int idx = p*256 + t;
    int d = idx >> 3, c8 = (idx & 7)*8;
    uint4 u;
    u.x = (unsigned)tile[c8+0][d] | ((unsigned)tile[c8+1][d] << 16);
    u.y = (unsigned)tile[c8+2][d] | ((unsigned)tile[c8+3][d] << 16);
    u.z = (unsigned)tile[c8+4][d] | ((unsigned)tile[c8+5][d] << 16);
    u.w = (unsigned)tile[c8+6][d] | ((unsigned)tile[c8+7][d] << 16);
    *(uint4*)(dstp + (size_t)d*64 + c8) = u;
  }
}

// ---------------- MFMA GEMM: bf16 A/B staging for BOTH modes ----------------
template<int MODE, int NCOLS>
__global__ __launch_bounds__(256) void mfma_gemm(
    const ushort_t* __restrict__ A,
    const ushort_t* __restrict__ BT,
    const float* __restrict__ bias,
    void* __restrict__ Cv)
{
  __shared__ __align__(16) unsigned char smem[17408];
  ushort_t (*As)[128][8] = (ushort_t(*)[128][8])smem;
  ushort_t (*Bs)[128][8] = (ushort_t(*)[128][8])(smem + 8192);

  int t = threadIdx.x;
  int lane = t & 63, w = t >> 6;
  int col = lane & 15, quad = lane >> 4;
  int n0 = blockIdx.x * 128, m0 = blockIdx.y * 128;
  int sr = t >> 1, h = t & 1;

  f32x4 acc[4][4];
  #pragma unroll
  for (int i = 0; i < 4; i++)
    #pragma unroll
    for (int j = 0; j < 4; j++) acc[i][j] = (f32x4){0.f,0.f,0.f,0.f};

  int mbase = (w & 1)*64 + col;
  int nbase = (w >> 1)*64 + col;

  for (int k0 = 0; k0 < DIM; k0 += 32){
    const ushort_t* ap = A + (size_t)(m0 + sr)*DIM + k0 + h*16;
    uint4 aa0 = *(const uint4*)ap, aa1 = *(const uint4*)(ap + 8);
    const ushort_t* bp = BT + (size_t)(n0 + sr)*DIM + k0 + h*16;
    uint4 bb0 = *(const uint4*)bp, bb1 = *(const uint4*)(bp + 8);

    __syncthreads();
    *(uint4*)&As[2*h  ][sr][0] = aa0;
    *(uint4*)&As[2*h+1][sr][0] = aa1;
    *(uint4*)&Bs[2*h  ][sr][0] = bb0;
    *(uint4*)&Bs[2*h+1][sr][0] = bb1;
    __syncthreads();

    bf16x8 af[4], bfr[4];
    #pragma unroll
    for (int i = 0; i < 4; i++){
      af[i]  = *(const bf16x8*)&As[quad][mbase + i*16][0];
      bfr[i] = *(const bf16x8*)&Bs[quad][nbase + i*16][0];
    }
    #pragma unroll
    for (int mt = 0; mt < 4; mt++)
      #pragma unroll
      for (int nt = 0; nt < 4; nt++)
        acc[mt][nt] = __builtin_amdgcn_mfma_f32_16x16x32_bf16(af[mt], bfr[nt], acc[mt][nt], 0, 0, 0);
  }

  float bscale = (MODE == 2 && n0 < 1024) ? QSCALE : 1.f;
  float bv[4];
  #pragma unroll
  for (int nt = 0; nt < 4; nt++) bv[nt] = bias[n0 + (w>>1)*64 + nt*16 + col] * bscale;

  if (MODE == 2){
    ushort_t (*Cs)[136] = (ushort_t(*)[136])smem;
    ushort_t* C = (ushort_t*)Cv;
    #pragma unroll
    for (int ph = 0; ph < 2; ph++){
      __syncthreads();
      if ((w & 1) == ph){
        #pragma unroll
        for (int mt = 0; mt < 4; mt++)
          #pragma unroll
          for (int nt = 0; nt < 4; nt++)
            #pragma unroll
            for (int r = 0; r < 4; r++)
              Cs[mt*16 + quad*4 + r][(w>>1)*64 + nt*16 + col] = f2bf(acc[mt][nt][r] + bv[nt]);
      }
      __syncthreads();
      #pragma unroll
      for (int p = 0; p < 4; p++){
        int id = p*256 + t;
        int row = id >> 4, cc = id & 15;
        uint4 u = *(const uint4*)&Cs[row][cc*8];
        int m = m0 + ph*64 + row;
        int n = n0 + cc*8;
        int which = n >> 10, hh = (n >> 6) & 15, d = n & 63;
        int b_ = m >> 11, s_ = m & (SEQ-1);
        *(uint4*)&C[((((size_t)which*BN + b_)*NH + hh)*SEQ + s_)*HDIM + d] = u;
      }
    }
  } else {
    float (*Cf)[132] = (float(*)[132])smem;
    float* C = (float*)Cv;
    #pragma unroll
    for (int ph = 0; ph < 4; ph++){
      __syncthreads();
      if ((w & 1) == (ph >> 1)){
        #pragma unroll
        for (int mi = 0; mi < 2; mi++){
          int mt = (ph & 1)*2 + mi;
          #pragma unroll
          for (int nt = 0; nt < 4; nt++)
            #pragma unroll
            for (int r = 0; r < 4; r++)
              Cf[mi*16 + quad*4 + r][(w>>1)*64 + nt*16 + col] = acc[mt][nt][r] + bv[nt];
        }
      }
      __syncthreads();
      #pragma unroll
      for (int p = 0; p < 4; p++){
        int id = p*256 + t;
        int row = id >> 5, cc = id & 31;
        float4 v = *(const float4*)&Cf[row][cc*4];
        int m = m0 + ph*32 + row;
        *(float4*)(C + (size_t)m*NCOLS + n0 + cc*4) = v;
      }
    }
  }
}

// ---------------- MFMA flash attention v8: 8-wave + XOR-swizzled LDS --------
// Round 6 changes vs v7b (verified r4/r5):
//  (1) 8 waves / 512 threads per block, 256 q rows per block: the SAME K/V
//      staging + barriers now feed 2x the compute -> staging ops, barriers,
//      and conflict totals per unit work all halve. Grid 1024 -> 512 blocks.
//  (2) K/V LDS layout row-major [64 rows][64 elems=128B] with G4 XOR swizzle:
//      16B-granule g of row r stored at g^(r&7). Puts staging b128 writes,
//      QK b128 reads AND PV 8B reads at the bank-usage floor (old oct-major
//      layout had sch outside the bank field -> 4-8 way collisions,
//      SQ_LDS_BANK_CONFLICT = 2.1e7/dispatch = ~32% of kernel cycles).
//      Logical layout unchanged -> v7's verified permutation algebra intact:
//      granule(row=key r, g) of K = dims g*8..+8; of V^T = keys g*8..+8 at
//      dim-row r. accL interleaved into PV loop (3 indep MFMA dep chains).
// KEY TRICK (v7, verified): MFMA k-perm invariance; V A-frag element j reads
// key 8*(j>>2)+4*half+(j&3) -> two 8B reads; raw P words used directly.
__global__ __launch_bounds__(512) void attn_kernel(const ushort_t* __restrict__ qkv,
                                                   const ushort_t* __restrict__ vtp,
                                                   ushort_t* __restrict__ ctx)
{
  __shared__ __align__(16) unsigned char lds[53248];   // K 8K | V 8K | Os 8x4608
  ushort_t* Ksm = (ushort_t*)lds;
  ushort_t* Vsm = (ushort_t*)(lds + 8192);

  int t = threadIdx.x;
  int lane = t & 63, w = t >> 6;         // w in [0,8)
  int m32 = lane & 31, half = lane >> 5;
  int r7 = m32 & 7;
  int id = blockIdx.x;                   // 512 blocks: 64 bh x 8 qb
  int bh = (id & 7) | ((id >> 6) << 3);  // XCD-swizzle (L2 locality)
  int qb = (id >> 3) & 7;

  const size_t PL = (size_t)BN * NH * SEQ * HDIM;
  const ushort_t* Qg = qkv + (size_t)bh * (SEQ * HDIM);
  const ushort_t* Kg = Qg + PL;
  const ushort_t* Vt = vtp + (size_t)bh * 32 * (HDIM * 64);
  int qbase = qb*256 + w*32;

  // Q B-frags: B[k=dim][n=q]: lane q=m32, dims c*16 + half*8 + [0,8)
  bf16x8 qf[4];
  #pragma unroll
  for (int c = 0; c < 4; c++)
    qf[c] = *(const bf16x8*)(Qg + (size_t)(qbase + m32)*HDIM + c*16 + half*8);

  bf16x8 ones;
  #pragma unroll
  for (int i = 0; i < 8; i++) ones[i] = (short)0x3F80;

  f32x16 accO[2], accL;
  #pragma unroll
  for (int i = 0; i < 2; i++)
    #pragma unroll
    for (int r = 0; r < 16; r++) accO[i][r] = 0.f;
  #pragma unroll
  for (int r = 0; r < 16; r++) accL[r] = 0.f;

  // staging: 512 threads x (one uint4 K + one uint4 V) = full 8KB tiles.
  // thread (srow=t>>3, och=t&7) loads granule och of row srow; global reads
  // stay coalesced (8 lanes = 128B contiguous row); LDS write at swizzled
  // granule och^(srow&7).
  int srow = t >> 3, och = t & 7;
  const ushort_t* kp0 = Kg + (size_t)srow*HDIM + och*8;
  const ushort_t* vp0 = Vt + (size_t)srow*64 + och*8;
  int wofs = srow*64 + ((och ^ (srow & 7)) << 3);

  uint4 kr = *(const uint4*)kp0;
  uint4 vr = *(const uint4*)vp0;

  for (int kt = 0; kt < 32; kt++){
    __syncthreads();
    *(uint4*)&Ksm[wofs] = kr;
    *(uint4*)&Vsm[wofs] = vr;
    __syncthreads();

    if (kt < 31){
      kr = *(const uint4*)(kp0 + (size_t)(kt+1)*64*HDIM);
      vr = *(const uint4*)(vp0 + (size_t)(kt+1)*HDIM*64);
    }

    // ---- per key-tile of 32: S^T = K Q^T, p = exp2(s), pack (RAW order) ----
    bf16x8 pb[4];
    #pragma unroll
    for (int mt = 0; mt < 2; mt++){
      f32x16 z;
      #pragma unroll
      for (int r = 0; r < 16; r++) z[r] = 0.f;
      int rowb = (mt*32 + m32) * 64;       // row = key; row&7 == r7
      #pragma unroll
      for (int c = 0; c < 4; c++){
        bf16x8 af = *(const bf16x8*)&Ksm[rowb + (((2*c + half) ^ r7) << 3)];
        z = __builtin_amdgcn_mfma_f32_32x32x16_bf16(af, qf[c], z, 0, 0, 0);
      }
      unsigned u[8];
      #pragma unroll
      for (int i = 0; i < 8; i++){
        float p0 = __builtin_amdgcn_exp2f(z[2*i]);
        float p1 = __builtin_amdgcn_exp2f(z[2*i+1]);
        bf16v2 hh; hh.x = (__bf16)p0; hh.y = (__bf16)p1;
        u[i] = __builtin_bit_cast(unsigned, hh);
      }
      #pragma unroll
      for (int cc = 0; cc < 2; cc++){
        union { uint4 q; bf16x8 b; } cvt;
        cvt.q = make_uint4(u[4*cc+0], u[4*cc+1], u[4*cc+2], u[4*cc+3]);
        pb[mt*2 + cc] = cvt.b;   // raw order: slot (h,e) holds key 8(e>>2)+4h+(e&3)
      }
    }

    // ---- PV + l-sum interleaved: 3 independent MFMA dep chains ----
    #pragma unroll
    for (int kc = 0; kc < 4; kc++){
      accL = __builtin_amdgcn_mfma_f32_32x32x16_bf16(ones, pb[kc], accL, 0, 0, 0);
      #pragma unroll
      for (int md = 0; md < 2; md++){
        int dd = md*32 + m32;              // row = dim; row&7 == r7
        int rowb = dd * 64;
        union { bf16x8 v8; uint2 u2[2]; } vv;
        vv.u2[0] = *(const uint2*)&Vsm[rowb + (((2*kc  ) ^ r7) << 3) + 4*half];
        vv.u2[1] = *(const uint2*)&Vsm[rowb + (((2*kc+1) ^ r7) << 3) + 4*half];
        accO[md] = __builtin_amdgcn_mfma_f32_32x32x16_bf16(vv.v8, pb[kc], accO[md], 0, 0, 0);
      }
    }
  }

  // ---- epilogue: l = accL[0]; Os disjoint + wave-private (no barriers) ----
  float inv = 1.f / accL[0];

  ushort_t (*Os)[72] = (ushort_t(*)[72])(lds + 16384 + w*4608);   // [32 q][64+8 d]
  #pragma unroll
  for (int md = 0; md < 2; md++)
    #pragma unroll
    for (int g = 0; g < 4; g++){
      int d0 = 8*g + 4*half + 32*md;
      unsigned lo = pack2(accO[md][4*g+0]*inv, accO[md][4*g+1]*inv);
      unsigned hi = pack2(accO[md][4*g+2]*inv, accO[md][4*g+3]*inv);
      *(uint2*)&Os[m32][d0] = make_uint2(lo, hi);
    }

  int b_ = bh >> 4, h_ = bh & 15;
  #pragma unroll
  for (int k = 0; k < 4; k++){
    int row = k*8 + (lane >> 3);
    uint4 u = *(const uint4*)&Os[row][(lane & 7)*8];
    *(uint4*)(ctx + ((size_t)(b_*SEQ + qb*256 + w*32 + row))*DIM + h_*HDIM + (lane & 7)*8) = u;
  }
}

extern "C" void kernel_launch(void* const* d_in, const int* in_sizes, int n_in,
                              void* d_out, int out_size, void* d_ws, size_t ws_size,
                              hipStream_t stream)
{
  const float* x      = (const float*)d_in[0];
  const float* gamma  = (const float*)d_in[1];
  const float* beta   = (const float*)d_in[2];
  const float* w_qkv  = (const float*)d_in[3];
  const float* b_qkv  = (const float*)d_in[4];
  const float* w_proj = (const float*)d_in[5];
  const float* b_proj = (const float*)d_in[6];

  // ws (64 MB), timeline-overlapped:
  //   wqkvT  0..6MB      (written cvt_t#1, read QKV GEMM)
  //   vt     0..16MB     (written vtrans after wqkvT dead, read attn)
  //   wprojT 0..2MB      (written cvt_t#2 after attn, read proj GEMM)
  //   qkv    16..64MB    (written QKV GEMM; Q,K read by attn; V by vtrans)
  //   ctx    48..64MB    (overwrites V plane after vtrans copied it)
  // xnb (16MB bf16 LN output) lives in the FIRST HALF OF d_out (32MB f32):
  // dead by the time the proj GEMM rewrites all of d_out; rewritten from x
  // every launch -> deterministic across graph replays.
  char* ws = (char*)d_ws;
  ushort_t* wqkvT  = (ushort_t*)ws;
  ushort_t* vt     = (ushort_t*)ws;
  ushort_t* wprojT = (ushort_t*)ws;
  ushort_t* qkv    = (ushort_t*)(ws + 16u*1024*1024);
  ushort_t* Vplane = (ushort_t*)(ws + 48u*1024*1024);
  ushort_t* ctx    = (ushort_t*)(ws + 48u*1024*1024);
  ushort_t* xnb    = (ushort_t*)d_out;

  ln_kernel<<<MROWS, 256, 0, stream>>>(x, gamma, beta, xnb);
  cvt_t<<<dim3(3*DIM/64, DIM/64), 256, 0, stream>>>(w_qkv, wqkvT, DIM, 3*DIM, QSCALE);
  mfma_gemm<2, 3*DIM><<<dim3(3*DIM/128, MROWS/128), 256, 0, stream>>>(
      xnb, wqkvT, b_qkv, qkv);
  vtrans<<<BN*NH*(SEQ/64), 256, 0, stream>>>(Vplane, vt);
  attn_kernel<<<BN*NH*(SEQ/256), 512, 0, stream>>>(qkv, vt, ctx);
  cvt_t<<<dim3(DIM/64, DIM/64), 256, 0, stream>>>(w_proj, wprojT, DIM, DIM, 1.f);
  mfma_gemm<0, DIM><<<dim3(DIM/128, MROWS/128), 256, 0, stream>>>(
      ctx, wprojT, b_proj, d_out);
}

// Round 9
// 305.114 us; speedup vs baseline: 1.3211x; 1.0282x over previous
//
#include <hip/hip_runtime.h>

typedef unsigned short ushort_t;
typedef __attribute__((ext_vector_type(8))) short bf16x8;
typedef __attribute__((ext_vector_type(4))) float f32x4;
typedef __attribute__((ext_vector_type(16))) float f32x16;
typedef __attribute__((ext_vector_type(2))) __bf16 bf16v2;

#define BN 4
#define SEQ 2048
#define DIM 1024
#define NH 16
#define HDIM 64
#define MROWS (BN*SEQ)   // 8192
#define QSCALE 0.18033688011112042f   // 0.125 * log2(e): folded into Q so p = exp2(s)

__device__ __forceinline__ float bf2f(ushort_t s){ return __uint_as_float(((unsigned)s) << 16); }
__device__ __forceinline__ ushort_t f2bf(float f){
  unsigned u = __float_as_uint(f);
  u += 0x7fffu + ((u >> 16) & 1u);   // round-to-nearest-even
  return (ushort_t)(u >> 16);
}
__device__ __forceinline__ unsigned pack2(float a, float b){
  return (unsigned)f2bf(a) | ((unsigned)f2bf(b) << 16);
}

// async global->LDS copy, 16B per lane; LDS dest = wave-uniform base + lane*16
#define GLL16(gp, lp) __builtin_amdgcn_global_load_lds( \
    (const __attribute__((address_space(1))) void*)(gp), \
    (__attribute__((address_space(3))) void*)(lp), 16, 0, 0)

// ------- fused LN: stats + normalize + bf16 pack, ONE pass over x -----------
__global__ __launch_bounds__(256) void ln_kernel(const float* __restrict__ x,
                                                 const float* __restrict__ gamma,
                                                 const float* __restrict__ beta,
                                                 ushort_t* __restrict__ xnb)
{
  int row = blockIdx.x;
  int t = threadIdx.x;
  float4 v = ((const float4*)(x + (size_t)row * DIM))[t];
  float s = v.x+v.y+v.z+v.w;
  float ss = v.x*v.x+v.y*v.y+v.z*v.z+v.w*v.w;
  #pragma unroll
  for (int o = 32; o > 0; o >>= 1){ s += __shfl_down(s, o); ss += __shfl_down(ss, o); }
  __shared__ float red[10];
  int wid = t >> 6;
  if ((t & 63) == 0){ red[wid] = s; red[4+wid] = ss; }
  __syncthreads();
  if (t == 0){
    float S0 = red[0]+red[1]+red[2]+red[3];
    float SS = red[4]+red[5]+red[6]+red[7];
    float mu = S0 * (1.f/DIM);
    float var = SS * (1.f/DIM) - mu*mu;
    red[8] = mu; red[9] = rsqrtf(var + 1e-5f);
  }
  __syncthreads();
  float mu = red[8], rstd = red[9];
  float4 g = ((const float4*)gamma)[t];
  float4 b = ((const float4*)beta)[t];
  float f0 = (v.x - mu)*rstd*g.x + b.x;
  float f1 = (v.y - mu)*rstd*g.y + b.y;
  float f2 = (v.z - mu)*rstd*g.z + b.z;
  float f3 = (v.w - mu)*rstd*g.w + b.w;
  *(uint2*)(xnb + (size_t)row*DIM + t*4) = make_uint2(pack2(f0,f1), pack2(f2,f3));
}

// ------- transpose + fp32->bf16 convert: dst[n][k] = src[k][n] * rowscale ---
__global__ __launch_bounds__(256) void cvt_t(const float* __restrict__ src,
                                             ushort_t* __restrict__ dst,
                                             int K, int N, float qscale)
{
  __shared__ float tile[64][65];
  int k0 = blockIdx.y*64, n0 = blockIdx.x*64;
  float sc = (n0 < 1024) ? qscale : 1.f;
  int t = threadIdx.x;
  int c = (t & 15) * 4, r = t >> 4;
  #pragma unroll
  for (int p = 0; p < 4; p++){
    float4 v = *(const float4*)(src + (size_t)(k0 + r + p*16)*N + n0 + c);
    tile[r+p*16][c]   = v.x; tile[r+p*16][c+1] = v.y;
    tile[r+p*16][c+2] = v.z; tile[r+p*16][c+3] = v.w;
  }
  __syncthreads();
  #pragma unroll
  for (int p = 0; p < 4; p++){
    int nn = r + p*16;
    ushort4 o;
    o.x = f2bf(tile[c+0][nn]*sc); o.y = f2bf(tile[c+1][nn]*sc);
    o.z = f2bf(tile[c+2][nn]*sc); o.w = f2bf(tile[c+3][nn]*sc);
    *(ushort4*)(dst + (size_t)(n0+nn)*K + k0 + c) = o;
  }
}

// ---------------- V transpose -> panel-contiguous V^T -----------------------
__global__ __launch_bounds__(256) void vtrans(const ushort_t* __restrict__ V,
                                              ushort_t* __restrict__ vt)
{
  __shared__ ushort_t tile[64][72];
  int bh = blockIdx.x >> 5, sc = blockIdx.x & 31;
  int t = threadIdx.x;
  const ushort_t* src = V + ((size_t)bh*SEQ + sc*64)*HDIM;
  #pragma unroll
  for (int p = 0; p < 2; p++){
    int idx = p*256 + t;
    int r = idx >> 3, c8 = (idx & 7)*8;
    *(uint4*)&tile[r][c8] = *(const uint4*)(src + (size_t)r*HDIM + c8);
  }
  __syncthreads();
  ushort_t* dstp = vt + ((size_t)(bh*32 + sc))*HDIM*64;
  #pragma unroll
  for (int p = 0; p < 2; p++){
    int idx = p*256 + t;
    int d = idx >> 3, c8 = (idx & 7)*8;
    uint4 u;
    u.x = (unsigned)tile[c8+0][d] | ((unsigned)tile[c8+1][d] << 16);
    u.y = (unsigned)tile[c8+2][d] | ((unsigned)tile[c8+3][d] << 16);
    u.z = (unsigned)tile[c8+4][d] | ((unsigned)tile[c8+5][d] << 16);
    u.w = (unsigned)tile[c8+6][d] | ((unsigned)tile[c8+7][d] << 16);
    *(uint4*)(dstp + (size_t)d*64 + c8) = u;
  }
}

// ---------------- MFMA GEMM v2: global_load_lds staging (round 9) -----------
// Round 9: reg-staging (2x uint4 per operand per thread + LDS stores) replaced
// by __builtin_amdgcn_global_load_lds width=16 (Common-mistake #1; m97 ladder
// step 3 = +67%). LDS tiles are row-major [128 rows][4 chunks x 8 elems]
// (linear in lane order as the DMA requires). To kill the 8-way read conflict
// of a 64B-row layout, the GLOBAL source is pre-swizzled (m173): physical
// chunk p of row r holds logical k-chunk p ^ swz(r), swz(r)=(r&3)^((r>>2)&3).
// Fragment reads then hit 8 distinct granules per 8-lane phase = all 32 banks
// (checked per-phase); the read-side swizzle folds to a per-lane constant
// (col&3)^((col>>2)&3). MFMA order and epilogues unchanged -> bitwise-equal C.
template<int MODE, int NCOLS>
__global__ __launch_bounds__(256) void mfma_gemm(
    const ushort_t* __restrict__ A,
    const ushort_t* __restrict__ BT,
    const float* __restrict__ bias,
    void* __restrict__ Cv)
{
  __shared__ __align__(16) unsigned char smem[17408];
  ushort_t* AsL = (ushort_t*)smem;             // [128][32] physical, 8KB
  ushort_t* BsL = (ushort_t*)(smem + 8192);    // [128][32] physical, 8KB

  int t = threadIdx.x;
  int lane = t & 63, w = t >> 6;
  int col = lane & 15, quad = lane >> 4;
  int n0 = blockIdx.x * 128, m0 = blockIdx.y * 128;

  f32x4 acc[4][4];
  #pragma unroll
  for (int i = 0; i < 4; i++)
    #pragma unroll
    for (int j = 0; j < 4; j++) acc[i][j] = (f32x4){0.f,0.f,0.f,0.f};

  int mbase = (w & 1)*64 + col;
  int nbase = (w >> 1)*64 + col;

  // ---- staging geometry: wave w owns segments {2w, 2w+1} of A and of B ----
  // segment s = 16 rows (1KB); lane i -> row s*16 + (i>>2), physical chunk i&3,
  // which must receive LOGICAL chunk (i&3) ^ swz(row).
  int r0 = (2*w  )*16 + (lane >> 2);
  int r1 = (2*w+1)*16 + (lane >> 2);
  int c0 = (((lane & 3) ^ ((r0 & 3) ^ ((r0 >> 2) & 3))) << 3);
  int c1 = (((lane & 3) ^ ((r1 & 3) ^ ((r1 >> 2) & 3))) << 3);
  const ushort_t* gA0 = A  + (size_t)(m0 + r0)*DIM + c0;
  const ushort_t* gA1 = A  + (size_t)(m0 + r1)*DIM + c1;
  const ushort_t* gB0 = BT + (size_t)(n0 + r0)*DIM + c0;
  const ushort_t* gB1 = BT + (size_t)(n0 + r1)*DIM + c1;
  unsigned char* lA0 = smem        + (2*w  )*1024;   // wave-uniform LDS bases
  unsigned char* lA1 = smem        + (2*w+1)*1024;
  unsigned char* lB0 = smem + 8192 + (2*w  )*1024;
  unsigned char* lB1 = smem + 8192 + (2*w+1)*1024;

  // read-side swizzle: per-lane constant (i*16 and 64*(w&1) are 0 mod the
  // swz fields, so swz(row) == (col&3)^((col>>2)&3) for every fragment row)
  int ppos = ((quad ^ ((col & 3) ^ ((col >> 2) & 3))) << 3);

  for (int k0 = 0; k0 < DIM; k0 += 32){
    __syncthreads();                       // all waves done reading prev tile
    GLL16(gA0 + k0, lA0);
    GLL16(gA1 + k0, lA1);
    GLL16(gB0 + k0, lB0);
    GLL16(gB1 + k0, lB1);
    __syncthreads();                       // compiler drains vmcnt before this

    bf16x8 af[4], bfr[4];
    #pragma unroll
    for (int i = 0; i < 4; i++){
      af[i]  = *(const bf16x8*)&AsL[(mbase + i*16)*32 + ppos];
      bfr[i] = *(const bf16x8*)&BsL[(nbase + i*16)*32 + ppos];
    }
    #pragma unroll
    for (int mt = 0; mt < 4; mt++)
      #pragma unroll
      for (int nt = 0; nt < 4; nt++)
        acc[mt][nt] = __builtin_amdgcn_mfma_f32_16x16x32_bf16(af[mt], bfr[nt], acc[mt][nt], 0, 0, 0);
  }

  float bscale = (MODE == 2 && n0 < 1024) ? QSCALE : 1.f;
  float bv[4];
  #pragma unroll
  for (int nt = 0; nt < 4; nt++) bv[nt] = bias[n0 + (w>>1)*64 + nt*16 + col] * bscale;

  if (MODE == 2){
    ushort_t (*Cs)[136] = (ushort_t(*)[136])smem;
    ushort_t* C = (ushort_t*)Cv;
    #pragma unroll
    for (int ph = 0; ph < 2; ph++){
      __syncthreads();
      if ((w & 1) == ph){
        #pragma unroll
        for (int mt = 0; mt < 4; mt++)
          #pragma unroll
          for (int nt = 0; nt < 4; nt++)
            #pragma unroll
            for (int r = 0; r < 4; r++)
              Cs[mt*16 + quad*4 + r][(w>>1)*64 + nt*16 + col] = f2bf(acc[mt][nt][r] + bv[nt]);
      }
      __syncthreads();
      #pragma unroll
      for (int p = 0; p < 4; p++){
        int id = p*256 + t;
        int row = id >> 4, cc = id & 15;
        uint4 u = *(const uint4*)&Cs[row][cc*8];
        int m = m0 + ph*64 + row;
        int n = n0 + cc*8;
        int which = n >> 10, hh = (n >> 6) & 15, d = n & 63;
        int b_ = m >> 11, s_ = m & (SEQ-1);
        *(uint4*)&C[((((size_t)which*BN + b_)*NH + hh)*SEQ + s_)*HDIM + d] = u;
      }
    }
  } else {
    float (*Cf)[132] = (float(*)[132])smem;
    float* C = (float*)Cv;
    #pragma unroll
    for (int ph = 0; ph < 4; ph++){
      __syncthreads();
      if ((w & 1) == (ph >> 1)){
        #pragma unroll
        for (int mi = 0; mi < 2; mi++){
          int mt = (ph & 1)*2 + mi;
          #pragma unroll
          for (int nt = 0; nt < 4; nt++)
            #pragma unroll
            for (int r = 0; r < 4; r++)
              Cf[mi*16 + quad*4 + r][(w>>1)*64 + nt*16 + col] = acc[mt][nt][r] + bv[nt];
        }
      }
      __syncthreads();
      #pragma unroll
      for (int p = 0; p < 4; p++){
        int id = p*256 + t;
        int row = id >> 5, cc = id & 31;
        float4 v = *(const float4*)&Cf[row][cc*4];
        int m = m0 + ph*32 + row;
        *(float4*)(C + (size_t)m*NCOLS + n0 + cc*4) = v;
      }
    }
  }
}

// ---------------- MFMA flash attention v8: 8-wave + XOR-swizzled LDS --------
// (verified round 8: 102.4us, MfmaUtil 37.6; unchanged this round)
// KEY TRICK (v7, verified): MFMA k-perm invariance; V A-frag element j reads
// key 8*(j>>2)+4*half+(j&3) -> two 8B reads; raw P words used directly.
__global__ __launch_bounds__(512) void attn_kernel(const ushort_t* __restrict__ qkv,
                                                   const ushort_t* __restrict__ vtp,
                                                   ushort_t* __restrict__ ctx)
{
  __shared__ __align__(16) unsigned char lds[53248];   // K 8K | V 8K | Os 8x4608
  ushort_t* Ksm = (ushort_t*)lds;
  ushort_t* Vsm = (ushort_t*)(lds + 8192);

  int t = threadIdx.x;
  int lane = t & 63, w = t >> 6;         // w in [0,8)
  int m32 = lane & 31, half = lane >> 5;
  int r7 = m32 & 7;
  int id = blockIdx.x;                   // 512 blocks: 64 bh x 8 qb
  int bh = (id & 7) | ((id >> 6) << 3);  // XCD-swizzle (L2 locality)
  int qb = (id >> 3) & 7;

  const size_t PL = (size_t)BN * NH * SEQ * HDIM;
  const ushort_t* Qg = qkv + (size_t)bh * (SEQ * HDIM);
  const ushort_t* Kg = Qg + PL;
  const ushort_t* Vt = vtp + (size_t)bh * 32 * (HDIM * 64);
  int qbase = qb*256 + w*32;

  // Q B-frags: B[k=dim][n=q]: lane q=m32, dims c*16 + half*8 + [0,8)
  bf16x8 qf[4];
  #pragma unroll
  for (int c = 0; c < 4; c++)
    qf[c] = *(const bf16x8*)(Qg + (size_t)(qbase + m32)*HDIM + c*16 + half*8);

  bf16x8 ones;
  #pragma unroll
  for (int i = 0; i < 8; i++) ones[i] = (short)0x3F80;

  f32x16 accO[2], accL;
  #pragma unroll
  for (int i = 0; i < 2; i++)
    #pragma unroll
    for (int r = 0; r < 16; r++) accO[i][r] = 0.f;
  #pragma unroll
  for (int r = 0; r < 16; r++) accL[r] = 0.f;

  // staging: 512 threads x (one uint4 K + one uint4 V) = full 8KB tiles.
  int srow = t >> 3, och = t & 7;
  const ushort_t* kp0 = Kg + (size_t)srow*HDIM + och*8;
  const ushort_t* vp0 = Vt + (size_t)srow*64 + och*8;
  int wofs = srow*64 + ((och ^ (srow & 7)) << 3);

  uint4 kr = *(const uint4*)kp0;
  uint4 vr = *(const uint4*)vp0;

  for (int kt = 0; kt < 32; kt++){
    __syncthreads();
    *(uint4*)&Ksm[wofs] = kr;
    *(uint4*)&Vsm[wofs] = vr;
    __syncthreads();

    if (kt < 31){
      kr = *(const uint4*)(kp0 + (size_t)(kt+1)*64*HDIM);
      vr = *(const uint4*)(vp0 + (size_t)(kt+1)*HDIM*64);
    }

    // ---- per key-tile of 32: S^T = K Q^T, p = exp2(s), pack (RAW order) ----
    bf16x8 pb[4];
    #pragma unroll
    for (int mt = 0; mt < 2; mt++){
      f32x16 z;
      #pragma unroll
      for (int r = 0; r < 16; r++) z[r] = 0.f;
      int rowb = (mt*32 + m32) * 64;       // row = key; row&7 == r7
      #pragma unroll
      for (int c = 0; c < 4; c++){
        bf16x8 af = *(const bf16x8*)&Ksm[rowb + (((2*c + half) ^ r7) << 3)];
        z = __builtin_amdgcn_mfma_f32_32x32x16_bf16(af, qf[c], z, 0, 0, 0);
      }
      unsigned u[8];
      #pragma unroll
      for (int i = 0; i < 8; i++){
        float p0 = __builtin_amdgcn_exp2f(z[2*i]);
        float p1 = __builtin_amdgcn_exp2f(z[2*i+1]);
        bf16v2 hh; hh.x = (__bf16)p0; hh.y = (__bf16)p1;
        u[i] = __builtin_bit_cast(unsigned, hh);
      }
      #pragma unroll
      for (int cc = 0; cc < 2; cc++){
        union { uint4 q; bf16x8 b; } cvt;
        cvt.q = make_uint4(u[4*cc+0], u[4*cc+1], u[4*cc+2], u[4*cc+3]);
        pb[mt*2 + cc] = cvt.b;   // raw order: slot (h,e) holds key 8(e>>2)+4h+(e&3)
      }
    }

    // ---- PV + l-sum interleaved: 3 independent MFMA dep chains ----
    #pragma unroll
    for (int kc = 0; kc < 4; kc++){
      accL = __builtin_amdgcn_mfma_f32_32x32x16_bf16(ones, pb[kc], accL, 0, 0, 0);
      #pragma unroll
      for (int md = 0; md < 2; md++){
        int dd = md*32 + m32;              // row = dim; row&7 == r7
        int rowb = dd * 64;
        union { bf16x8 v8; uint2 u2[2]; } vv;
        vv.u2[0] = *(const uint2*)&Vsm[rowb + (((2*kc  ) ^ r7) << 3) + 4*half];
        vv.u2[1] = *(const uint2*)&Vsm[rowb + (((2*kc+1) ^ r7) << 3) + 4*half];
        accO[md] = __builtin_amdgcn_mfma_f32_32x32x16_bf16(vv.v8, pb[kc], accO[md], 0, 0, 0);
      }
    }
  }

  // ---- epilogue: l = accL[0]; Os disjoint + wave-private (no barriers) ----
  float inv = 1.f / accL[0];

  ushort_t (*Os)[72] = (ushort_t(*)[72])(lds + 16384 + w*4608);   // [32 q][64+8 d]
  #pragma unroll
  for (int md = 0; md < 2; md++)
    #pragma unroll
    for (int g = 0; g < 4; g++){
      int d0 = 8*g + 4*half + 32*md;
      unsigned lo = pack2(accO[md][4*g+0]*inv, accO[md][4*g+1]*inv);
      unsigned hi = pack2(accO[md][4*g+2]*inv, accO[md][4*g+3]*inv);
      *(uint2*)&Os[m32][d0] = make_uint2(lo, hi);
    }

  int b_ = bh >> 4, h_ = bh & 15;
  #pragma unroll
  for (int k = 0; k < 4; k++){
    int row = k*8 + (lane >> 3);
    uint4 u = *(const uint4*)&Os[row][(lane & 7)*8];
    *(uint4*)(ctx + ((size_t)(b_*SEQ + qb*256 + w*32 + row))*DIM + h_*HDIM + (lane & 7)*8) = u;
  }
}

extern "C" void kernel_launch(void* const* d_in, const int* in_sizes, int n_in,
                              void* d_out, int out_size, void* d_ws, size_t ws_size,
                              hipStream_t stream)
{
  const float* x      = (const float*)d_in[0];
  const float* gamma  = (const float*)d_in[1];
  const float* beta   = (const float*)d_in[2];
  const float* w_qkv  = (const float*)d_in[3];
  const float* b_qkv  = (const float*)d_in[4];
  const float* w_proj = (const float*)d_in[5];
  const float* b_proj = (const float*)d_in[6];

  // ws (64 MB), timeline-overlapped:
  //   wqkvT  0..6MB      (written cvt_t#1, read QKV GEMM)
  //   vt     0..16MB     (written vtrans after wqkvT dead, read attn)
  //   wprojT 0..2MB      (written cvt_t#2 after attn, read proj GEMM)
  //   qkv    16..64MB    (written QKV GEMM; Q,K read by attn; V by vtrans)
  //   ctx    48..64MB    (overwrites V plane after vtrans copied it)
  // xnb (16MB bf16 LN output) lives in the FIRST HALF OF d_out (32MB f32):
  // dead by the time the proj GEMM rewrites all of d_out; rewritten from x
  // every launch -> deterministic across graph replays.
  char* ws = (char*)d_ws;
  ushort_t* wqkvT  = (ushort_t*)ws;
  ushort_t* vt     = (ushort_t*)ws;
  ushort_t* wprojT = (ushort_t*)ws;
  ushort_t* qkv    = (ushort_t*)(ws + 16u*1024*1024);
  ushort_t* Vplane = (ushort_t*)(ws + 48u*1024*1024);
  ushort_t* ctx    = (ushort_t*)(ws + 48u*1024*1024);
  ushort_t* xnb    = (ushort_t*)d_out;

  ln_kernel<<<MROWS, 256, 0, stream>>>(x, gamma, beta, xnb);
  cvt_t<<<dim3(3*DIM/64, DIM/64), 256, 0, stream>>>(w_qkv, wqkvT, DIM, 3*DIM, QSCALE);
  mfma_gemm<2, 3*DIM><<<dim3(3*DIM/128, MROWS/128), 256, 0, stream>>>(
      xnb, wqkvT, b_qkv, qkv);
  vtrans<<<BN*NH*(SEQ/64), 256, 0, stream>>>(Vplane, vt);
  attn_kernel<<<BN*NH*(SEQ/256), 512, 0, stream>>>(qkv, vt, ctx);
  cvt_t<<<dim3(DIM/64, DIM/64), 256, 0, stream>>>(w_proj, wprojT, DIM, DIM, 1.f);
  mfma_gemm<0, DIM><<<dim3(DIM/128, MROWS/128), 256, 0, stream>>>(
      ctx, wprojT, b_proj, d_out);
}